// Round 11
// baseline (322.683 us; speedup 1.0000x reference)
//
#include <hip/hip_runtime.h>

#define BB 32
#define HH 512
#define WW 512
#define HW (HH * WW)
#define NPIX (BB * HH * WW)

// strip: 64 wide x 256 tall; 8 bands of 32 rows; grid (8,2,32)=512 blocks
// m-ring: 64 rows x 84 floats (21 quads; 20 data = cols [x0-8..x0+71])
// q-ring: 64 rows x 76 floats (19 quads; 18 data = cols [x0-4..x0+67])
// e-ring: 128 rows x 76 floats (18 data quads = cols [x0-4..x0+67])
#define MSQ 21
#define QSQ 19
#define ESQ 19

// load 12 consecutive floats (3 quads) from LDS into dst[12]
#define LOADROW12(dst, p4, base)                                              \
    {                                                                         \
        float4 A_ = (p4)[base], B_ = (p4)[(base) + 1], C_ = (p4)[(base) + 2]; \
        (dst)[0] = A_.x; (dst)[1] = A_.y; (dst)[2]  = A_.z; (dst)[3]  = A_.w; \
        (dst)[4] = B_.x; (dst)[5] = B_.y; (dst)[6]  = B_.z; (dst)[7]  = B_.w; \
        (dst)[8] = C_.x; (dst)[9] = C_.y; (dst)[10] = C_.z; (dst)[11] = C_.w; \
    }

// 2x4 blur (r6/r7-proven 2-row register ring; parity static after unroll).
// rb = ring-row index of first window row; rows masked by MASK (pow2 ring).
#define BLUR2x4(p4, SQ, MASK, rb, cq, a0, a1)                                 \
    {                                                                         \
        float g0[12], g1[12];                                                 \
        LOADROW12(g0, p4, (((rb) + 0) & (MASK)) * (SQ) + (cq));               \
        _Pragma("unroll")                                                     \
        for (int ky = 0; ky < 9; ++ky) {                                      \
            float w[9];                                                       \
            _Pragma("unroll")                                                 \
            for (int kx = 0; kx < 9; ++kx) w[kx] = kw[ky * 9 + kx];           \
            if ((ky & 1) == 0) {                                              \
                LOADROW12(g1, p4, (((rb) + ky + 1) & (MASK)) * (SQ) + (cq));  \
                _Pragma("unroll")                                             \
                for (int kx = 0; kx < 9; ++kx)                                \
                    _Pragma("unroll")                                         \
                    for (int mx = 0; mx < 4; ++mx) {                          \
                        a0[mx] = fmaf(w[kx], g0[mx + kx], a0[mx]);            \
                        a1[mx] = fmaf(w[kx], g1[mx + kx], a1[mx]);            \
                    }                                                         \
            } else {                                                          \
                LOADROW12(g0, p4, (((rb) + ky + 1) & (MASK)) * (SQ) + (cq));  \
                _Pragma("unroll")                                             \
                for (int kx = 0; kx < 9; ++kx)                                \
                    _Pragma("unroll")                                         \
                    for (int mx = 0; mx < 4; ++mx) {                          \
                        a0[mx] = fmaf(w[kx], g1[mx + kx], a0[mx]);            \
                        a1[mx] = fmaf(w[kx], g0[mx + kx], a1[mx]);            \
                    }                                                         \
            }                                                                 \
        }                                                                     \
    }

// 1x4 blur for edge rows
#define BLUR1x4(p4, SQ, MASK, rb, cq, a0)                                     \
    {                                                                         \
        _Pragma("unroll")                                                     \
        for (int ky = 0; ky < 9; ++ky) {                                      \
            float g[12];                                                      \
            LOADROW12(g, p4, (((rb) + ky) & (MASK)) * (SQ) + (cq));           \
            _Pragma("unroll")                                                 \
            for (int kx = 0; kx < 9; ++kx) {                                  \
                float w_ = kw[ky * 9 + kx];                                   \
                _Pragma("unroll")                                             \
                for (int mx = 0; mx < 4; ++mx)                                \
                    a0[mx] = fmaf(w_, g[mx + kx], a0[mx]);                    \
            }                                                                 \
        }                                                                     \
    }

// ---------------------------------------------------------------------------
// k_stats: strip-pipelined fused stats. Per band k: stage m,q band k+1 ->
// blur m -> lm band k (global) + e band k (e-ring) -> blur e -> sigma band
// k-1 (global) + partial sum. m,q,e never touch HBM. LDS 78 KB -> 2/CU.
// ---------------------------------------------------------------------------
__global__ __launch_bounds__(256) void k_stats(const float* __restrict__ x,
                                               const float* __restrict__ kw,
                                               float* __restrict__ lm,
                                               float* __restrict__ sg,
                                               float* __restrict__ psums) {
    __shared__ float mt[64 * 84];
    __shared__ float qt[64 * 76];
    __shared__ float et[128 * 76];
    __shared__ float wsum[4];
    const int tx = threadIdx.x, ty = threadIdx.y;     // 16 x 16
    const int tid = ty * 16 + tx;

    // XCD swizzle (bijective, 512 % 8 == 0): each XCD gets 4 whole images
    int flat = (blockIdx.z * 2 + blockIdx.y) * 8 + blockIdx.x;
    int logi = (flat & 7) * 64 + (flat >> 3);
    const int lx = logi & 7, ly = (logi >> 3) & 1, lz = logi >> 4;
    const int x0 = lx * 64, y0 = ly * 256;
    const size_t boff = (size_t)lz * HW;
    const float4* x4 = (const float4*)(x + boff * 3);
    float4* m4 = (float4*)mt;
    float4* q4 = (float4*)qt;
    float4* e4 = (float4*)et;
    const float t3 = 1.f / 3.f;

    float ssum = 0.f;

    // stage m,q for band j: m rows mu=[32j..32j+31] (gy = y0+mu-8), 20 quads
    auto STAGE = [&](int j) {
        int nq = (j == 8) ? 320 : 640;
#pragma unroll
        for (int it = 0; it < 3; ++it) {
            int i = tid + 256 * it;
            if (i < nq) {
                int r = i / 20, qd = i - r * 20;
                int mu = 32 * j + r;
                int gy = y0 + mu - 8;
                int gx = x0 + 4 * qd - 8;
                float4 m = make_float4(0.f, 0.f, 0.f, 0.f);
                float4 qv = make_float4(0.f, 0.f, 0.f, 0.f);
                if (gy >= 0 && gy < HH && gx >= 0 && gx < WW) {
                    int go = (gy * WW + gx) >> 2;
                    float4 a = x4[3 * go + 0], b = x4[3 * go + 1], c = x4[3 * go + 2];
                    m.x = (a.x + a.y + a.z) * t3;  qv.x = (a.x * a.x + a.y * a.y + a.z * a.z) * t3;
                    m.y = (a.w + b.x + b.y) * t3;  qv.y = (a.w * a.w + b.x * b.x + b.y * b.y) * t3;
                    m.z = (b.z + b.w + c.x) * t3;  qv.z = (b.z * b.z + b.w * b.w + c.x * c.x) * t3;
                    m.w = (c.y + c.z + c.w) * t3;  qv.w = (c.y * c.y + c.z * c.z + c.w * c.w) * t3;
                }
                m4[(mu & 63) * MSQ + qd] = m;
                if (qd >= 1 && qd <= 18) q4[(mu & 63) * QSQ + (qd - 1)] = qv;
            }
        }
    };

    // e for one quad given lm(l), center m(mm), q(qq); zero handled by caller
    auto EQUAD = [&](float4 qq, float4 mm, float l0, float l1, float l2, float l3) {
        float4 e;
        e.x = fmaxf(qq.x - l0 * (2.f * mm.x - l0), 0.f);
        e.y = fmaxf(qq.y - l1 * (2.f * mm.y - l1), 0.f);
        e.z = fmaxf(qq.z - l2 * (2.f * mm.z - l2), 0.f);
        e.w = fmaxf(qq.w - l3 * (2.f * mm.w - l3), 0.f);
        return e;
    };

    STAGE(0);                                         // prologue

#pragma unroll 1
    for (int k = 0; k <= 8; ++k) {
        if (k <= 7) STAGE(k + 1);
        __syncthreads();

        if (k <= 7) {
            // ---- e band k: 288 units (16 row-pairs x 18 quads), 2x4 blur ----
#pragma unroll 1
            for (int u = tid; u < 288; u += 256) {
                int tr = u / 18, qe = u - tr * 18;
                int R0 = y0 + 32 * k + 2 * tr;        // in [y0..y0+255]
                int rbm = 32 * k + 2 * tr + 4;        // mu of first window row
                float a0[4] = {0.f, 0.f, 0.f, 0.f}, a1[4] = {0.f, 0.f, 0.f, 0.f};
                BLUR2x4((const float4*)mt, MSQ, 63, rbm, qe, a0, a1);
                if (qe >= 1 && qe <= 16) {            // interior lm write
                    float* lp = lm + boff + (size_t)R0 * WW + x0 + 4 * (qe - 1);
                    *(float4*)lp = make_float4(a0[0], a0[1], a0[2], a0[3]);
                    *(float4*)(lp + WW) = make_float4(a1[0], a1[1], a1[2], a1[3]);
                }
                int exq = x0 - 4 + 4 * qe;
                float4 e0 = make_float4(0.f, 0.f, 0.f, 0.f), e1 = e0;
                if (exq >= 0 && exq < WW) {
                    int mu0 = 32 * k + 2 * tr + 8;
                    float4 mm0 = m4[(mu0 & 63) * MSQ + qe + 1];
                    float4 mm1 = m4[((mu0 + 1) & 63) * MSQ + qe + 1];
                    float4 qq0 = q4[(mu0 & 63) * QSQ + qe];
                    float4 qq1 = q4[((mu0 + 1) & 63) * QSQ + qe];
                    e0 = EQUAD(qq0, mm0, a0[0], a0[1], a0[2], a0[3]);
                    e1 = EQUAD(qq1, mm1, a1[0], a1[1], a1[2], a1[3]);
                }
                int ep = 32 * k + 2 * tr + 4;         // eps of R0
                e4[(ep & 127) * ESQ + qe] = e0;
                e4[((ep + 1) & 127) * ESQ + qe] = e1;
            }
            if (k == 0 && tid < 72) {                 // top edge rows y0-4..y0-1
                int er = tid / 18, qe = tid - er * 18;
                int R = y0 - 4 + er;
                float a0[4] = {0.f, 0.f, 0.f, 0.f};
                BLUR1x4((const float4*)mt, MSQ, 63, er, qe, a0);
                int exq = x0 - 4 + 4 * qe;
                float4 e0 = make_float4(0.f, 0.f, 0.f, 0.f);
                if (R >= 0 && exq >= 0 && exq < WW) {
                    int mu = er + 4;
                    e0 = EQUAD(q4[(mu & 63) * QSQ + qe], m4[(mu & 63) * MSQ + qe + 1],
                               a0[0], a0[1], a0[2], a0[3]);
                }
                e4[(er & 127) * ESQ + qe] = e0;       // eps = er
            }
            if (k == 7 && tid < 72) {                 // bottom edge rows y0+256..259
                int er = tid / 18, qe = tid - er * 18;
                int R = y0 + 256 + er;
                float a0[4] = {0.f, 0.f, 0.f, 0.f};
                BLUR1x4((const float4*)mt, MSQ, 63, 260 + er, qe, a0);
                int exq = x0 - 4 + 4 * qe;
                float4 e0 = make_float4(0.f, 0.f, 0.f, 0.f);
                if (R < HH && exq >= 0 && exq < WW) {
                    int mu = 264 + er;
                    e0 = EQUAD(q4[(mu & 63) * QSQ + qe], m4[(mu & 63) * MSQ + qe + 1],
                               a0[0], a0[1], a0[2], a0[3]);
                }
                e4[((260 + er) & 127) * ESQ + qe] = e0;
            }
        }
        __syncthreads();

        if (k >= 1) {
            // ---- sigma band s=k-1: 256 units (16x16), 2x4 blur over e ----
            int s = k - 1;
            int S0 = y0 + 32 * s + 2 * ty;
            int rbe = 32 * s + 2 * ty;                // eps of first window row
            float a0[4] = {0.f, 0.f, 0.f, 0.f}, a1[4] = {0.f, 0.f, 0.f, 0.f};
            BLUR2x4((const float4*)et, ESQ, 127, rbe, tx, a0, a1);
            float4 o0, o1;
            o0.x = sqrtf(fmaxf(a0[0], 0.f)); o0.y = sqrtf(fmaxf(a0[1], 0.f));
            o0.z = sqrtf(fmaxf(a0[2], 0.f)); o0.w = sqrtf(fmaxf(a0[3], 0.f));
            o1.x = sqrtf(fmaxf(a1[0], 0.f)); o1.y = sqrtf(fmaxf(a1[1], 0.f));
            o1.z = sqrtf(fmaxf(a1[2], 0.f)); o1.w = sqrtf(fmaxf(a1[3], 0.f));
            float* dp = sg + boff + (size_t)S0 * WW + x0 + 4 * tx;
            *(float4*)dp = o0;
            *(float4*)(dp + WW) = o1;
            ssum += o0.x + o0.y + o0.z + o0.w + o1.x + o1.y + o1.z + o1.w;
        }
    }

    // ---- block reduction -> psums[strip] ----
#pragma unroll
    for (int off = 32; off > 0; off >>= 1) ssum += __shfl_down(ssum, off);
    if ((tid & 63) == 0) wsum[tid >> 6] = ssum;
    __syncthreads();
    if (tid == 0)
        psums[lz * 16 + ly * 8 + lx] = wsum[0] + wsum[1] + wsum[2] + wsum[3];
}

// ---------------------------------------------------------------------------
// k_norm: out = (x - lm) / max(mean_sigma_b, sigma); reduces 16 partials.
// ---------------------------------------------------------------------------
__global__ __launch_bounds__(256) void k_norm(const float4* __restrict__ x4,
                                              const float4* __restrict__ lm4,
                                              const float4* __restrict__ sg4,
                                              const float* __restrict__ psums,
                                              float4* __restrict__ out4) {
    __shared__ float msh;
    int g = blockIdx.x * 256 + threadIdx.x;
    int b = g >> 16;                                  // g / (HW/4); uniform per block
    float s = 0.f;
    if (threadIdx.x < 16) s = psums[b * 16 + threadIdx.x];
#pragma unroll
    for (int off = 32; off > 0; off >>= 1) s += __shfl_down(s, off);
    if (threadIdx.x == 0) msh = s * (1.f / (float)HW);
    __syncthreads();
    float ms = msh;

    float4 l = lm4[g];
    float4 sv = sg4[g];
    float i0 = 1.f / fmaxf(ms, sv.x);
    float i1 = 1.f / fmaxf(ms, sv.y);
    float i2 = 1.f / fmaxf(ms, sv.z);
    float i3 = 1.f / fmaxf(ms, sv.w);
    float4 a = x4[3 * g + 0];
    float4 bb = x4[3 * g + 1];
    float4 c = x4[3 * g + 2];
    float4 o0, o1, o2;
    o0.x = (a.x - l.x) * i0;  o0.y = (a.y - l.x) * i0;  o0.z = (a.z - l.x) * i0;
    o0.w = (a.w - l.y) * i1;  o1.x = (bb.x - l.y) * i1; o1.y = (bb.y - l.y) * i1;
    o1.z = (bb.z - l.z) * i2; o1.w = (bb.w - l.z) * i2; o2.x = (c.x - l.z) * i2;
    o2.y = (c.y - l.w) * i3;  o2.z = (c.z - l.w) * i3;  o2.w = (c.w - l.w) * i3;
    out4[3 * g + 0] = o0;
    out4[3 * g + 1] = o1;
    out4[3 * g + 2] = o2;
}

extern "C" void kernel_launch(void* const* d_in, const int* in_sizes, int n_in,
                              void* d_out, int out_size, void* d_ws, size_t ws_size,
                              hipStream_t stream) {
    const float* x = (const float*)d_in[0];
    const float* kw = (const float*)d_in[1];
    float* out = (float*)d_out;
    float* wsp = (float*)d_ws;
    float* lmb = wsp;                                 // NPIX floats
    float* sgb = wsp + (size_t)NPIX;                  // NPIX floats
    float* ps  = wsp + 2 * (size_t)NPIX;              // 512 floats

    dim3 blk(16, 16);
    dim3 grd(8, 2, BB);
    k_stats<<<grd, blk, 0, stream>>>(x, kw, lmb, sgb, ps);

    k_norm<<<NPIX / 4 / 256, 256, 0, stream>>>((const float4*)x, (const float4*)lmb,
                                               (const float4*)sgb, ps, (float4*)out);
}